// Round 1
// baseline (326.401 us; speedup 1.0000x reference)
//
#include <hip/hip_runtime.h>
#include <math.h>

#define TW 32
#define TH 32
#define SW 42          // TW + 10 halo
#define SH 42          // TH + 10 halo
#define SPITCH 44      // padded pitch for staged tile
#define HPITCH 33      // pitch for horizontally-filtered arrays (32+1)
#define BLOCK 256

// ---------------------------------------------------------------------------
// Kernel 1: one block per 32x32 output tile. Separable 11-tap Gaussian conv
// of 5 channels (p, y, p^2, y^2, p*y) with zero padding, fused SSIM map,
// block-level partial sum written to d_ws.
// ---------------------------------------------------------------------------
__global__ __launch_bounds__(BLOCK) void ssim_tile_kernel(
    const float* __restrict__ pred, const float* __restrict__ yin,
    float* __restrict__ partial, int W, int H)
{
    __shared__ float g[11];
    __shared__ float sp[SH * SPITCH];
    __shared__ float sy[SH * SPITCH];
    __shared__ float hp [SH * HPITCH];
    __shared__ float hy [SH * HPITCH];
    __shared__ float hp2[SH * HPITCH];
    __shared__ float hy2[SH * HPITCH];
    __shared__ float hpy[SH * HPITCH];
    __shared__ float wsum[BLOCK / 64];

    const int tid = threadIdx.x;
    const int x0 = blockIdx.x * TW;
    const int y0 = blockIdx.y * TH;
    const size_t base = (size_t)blockIdx.z * (size_t)H * (size_t)W;

    // Gaussian window (sigma=1.5, ws=11), computed in double to match the
    // numpy float64 window to <=1 f32 ulp after normalization.
    if (tid == 0) {
        double gd[11];
        double s = 0.0;
        #pragma unroll
        for (int i = 0; i < 11; ++i) {
            int d = i - 5;
            gd[i] = exp(-(double)(d * d) / 4.5);
            s += gd[i];
        }
        #pragma unroll
        for (int i = 0; i < 11; ++i) g[i] = (float)(gd[i] / s);
    }

    // ---- stage 42x42 halo'd tile (zero padding outside image) ----
    for (int idx = tid; idx < SH * SW; idx += BLOCK) {
        int r = idx / SW;
        int c = idx - r * SW;
        int gx = x0 + c - 5;
        int gy = y0 + r - 5;
        float vp = 0.f, vy = 0.f;
        if (gx >= 0 && gx < W && gy >= 0 && gy < H) {
            size_t o = base + (size_t)gy * (size_t)W + (size_t)gx;
            vp = pred[o];
            vy = yin[o];
        }
        sp[r * SPITCH + c] = vp;
        sy[r * SPITCH + c] = vy;
    }
    __syncthreads();

    float gr[11];
    #pragma unroll
    for (int i = 0; i < 11; ++i) gr[i] = g[i];   // broadcast reads -> registers

    // ---- horizontal pass: 42 rows x 32 cols, 5 channels ----
    for (int idx = tid; idx < SH * TW; idx += BLOCK) {
        int r = idx >> 5;        // TW == 32
        int c = idx & 31;
        const float* rp = &sp[r * SPITCH + c];
        const float* ry = &sy[r * SPITCH + c];
        float ap = 0.f, ay = 0.f, ap2 = 0.f, ay2 = 0.f, apy = 0.f;
        #pragma unroll
        for (int i = 0; i < 11; ++i) {
            float w = gr[i];
            float p = rp[i];
            float q = ry[i];
            ap  += w * p;
            ay  += w * q;
            ap2 += w * (p * p);
            ay2 += w * (q * q);
            apy += w * (p * q);
        }
        int o = r * HPITCH + c;
        hp [o] = ap;
        hy [o] = ay;
        hp2[o] = ap2;
        hy2[o] = ay2;
        hpy[o] = apy;
    }
    __syncthreads();

    // ---- vertical pass + SSIM map, 4 pixels per thread ----
    const float C1f = 1e-4f;      // 0.01^2
    const float C2f = 9e-4f;      // 0.03^2
    const int c  = tid & 31;
    const int r0 = (tid >> 5) * 4;

    float lsum = 0.f;
    #pragma unroll
    for (int rr = 0; rr < 4; ++rr) {
        int r = r0 + rr;
        float mu1 = 0.f, mu2 = 0.f, m11 = 0.f, m22 = 0.f, m12 = 0.f;
        #pragma unroll
        for (int j = 0; j < 11; ++j) {
            float w = gr[j];
            int o = (r + j) * HPITCH + c;
            mu1 += w * hp [o];
            mu2 += w * hy [o];
            m11 += w * hp2[o];
            m22 += w * hy2[o];
            m12 += w * hpy[o];
        }
        float mu1s = mu1 * mu1;
        float mu2s = mu2 * mu2;
        float mu12 = mu1 * mu2;
        float s1  = m11 - mu1s;
        float s2  = m22 - mu2s;
        float s12 = m12 - mu12;
        float num = (2.f * mu12 + C1f) * (2.f * s12 + C2f) * (s12 + 0.5f * C2f);
        float den = (mu1s + mu2s + C1f) * (s1 + s2 + C2f) * (sqrtf(s1 * s2) + 0.5f * C2f);
        lsum += num / den;
    }

    // ---- block reduction (wave shuffle + LDS) ----
    #pragma unroll
    for (int off = 32; off > 0; off >>= 1)
        lsum += __shfl_xor(lsum, off);
    int wid  = tid >> 6;
    int lane = tid & 63;
    if (lane == 0) wsum[wid] = lsum;
    __syncthreads();
    if (tid == 0) {
        float s = 0.f;
        #pragma unroll
        for (int w = 0; w < BLOCK / 64; ++w) s += wsum[w];
        int bid = (blockIdx.z * gridDim.y + blockIdx.y) * gridDim.x + blockIdx.x;
        partial[bid] = s;
    }
}

// ---------------------------------------------------------------------------
// Kernel 2: deterministic final reduction in double, writes scalar mean.
// ---------------------------------------------------------------------------
__global__ __launch_bounds__(1024) void ssim_reduce_kernel(
    const float* __restrict__ partial, int n, float* __restrict__ out, double scale)
{
    __shared__ double sd[1024];
    double s = 0.0;
    for (int i = threadIdx.x; i < n; i += 1024) s += (double)partial[i];
    sd[threadIdx.x] = s;
    __syncthreads();
    #pragma unroll
    for (int stride = 512; stride > 0; stride >>= 1) {
        if (threadIdx.x < stride) sd[threadIdx.x] += sd[threadIdx.x + stride];
        __syncthreads();
    }
    if (threadIdx.x == 0) out[0] = (float)(sd[0] * scale);
}

extern "C" void kernel_launch(void* const* d_in, const int* in_sizes, int n_in,
                              void* d_out, int out_size, void* d_ws, size_t ws_size,
                              hipStream_t stream)
{
    const float* pred = (const float*)d_in[0];
    const float* yin  = (const float*)d_in[1];
    float* out     = (float*)d_out;
    float* partial = (float*)d_ws;

    const int B = 32, H = 768, W = 768;
    dim3 grid(W / TW, H / TH, B);   // 24 x 24 x 32 = 18432 blocks

    ssim_tile_kernel<<<grid, BLOCK, 0, stream>>>(pred, yin, partial, W, H);

    const int nPartial = (W / TW) * (H / TH) * B;
    const double scale = 1.0 / ((double)B * (double)H * (double)W);
    ssim_reduce_kernel<<<1, 1024, 0, stream>>>(partial, nPartial, out, scale);
}